// Round 13
// baseline (71.340 us; speedup 1.0000x reference)
//
#include <hip/hip_runtime.h>
#include <hip/hip_bf16.h>

#define NPTS 32768
#define NSLAB 16
#define NF 128
#define HDIM 128
#define KDIM 512          // 4*NF
#define PTS_PER_BLK 64
#define MAXBLK 2064       // worst-case work items (4-slab membership bound)

// ---- workspace layout (bytes) ----
// [0, 64)        : g_count[16] (int)
// [1024, +1MB)   : lists, u16 [16][NPTS]
// [1.5MB, +8.3KB): work table: [0]=total, [1+i]=(s<<16)|blk
// [2MB, 4MB)     : tau_all, f32 [16][NPTS]
// [4MB, 6MB)     : W1T bf16 [16][128][512]  (K-permuted: k' = f*4+type)
// [6MB, 6.5MB)   : W2T bf16 [16][128][128]
#define WS_COUNT_OFF   0
#define WS_LIST_OFF    1024
#define WS_TABLE_OFF   0x180000
#define WS_TAU_OFF     (2u << 20)
#define WS_W1T_OFF     (4u << 20)
#define WS_W2T_OFF     (6u << 20)

typedef __attribute__((ext_vector_type(8))) short bf16x8;
typedef __attribute__((ext_vector_type(4))) float f32x4;
typedef __attribute__((ext_vector_type(4))) unsigned int u32x4;

__device__ __forceinline__ unsigned short f2bf(float f) {
    union { float f; unsigned u; } v; v.f = f;
    unsigned u = v.u;
    return (unsigned short)((u + 0x7FFFu + ((u >> 16) & 1u)) >> 16);
}
__device__ __forceinline__ float bf2f(unsigned short h) {
    union { unsigned u; float f; } v; v.u = ((unsigned)h) << 16; return v.f;
}
__device__ __forceinline__ float fast_tanh(float v) {
    v = fminf(fmaxf(v, -15.0f), 15.0f);
    float t = __builtin_amdgcn_exp2f(v * 2.8853900817779268f); // e^{2v}
    return (t - 1.0f) * __builtin_amdgcn_rcpf(t + 1.0f);
}
// pack two f32 -> one u32 of two bf16 (lo = a, hi = b)
__device__ __forceinline__ unsigned pk_bf16(float a, float b) {
    unsigned r;
    asm("v_cvt_pk_bf16_f32 %0, %1, %2" : "=v"(r) : "v"(a), "v"(b));
    return r;
}

// Transpose + f32->bf16 for W1 (K-permuted) and W2 in one launch (r5-proven).
// blockIdx.x < 64: W1 tile; else W2 tile.  32x32 tiles, 256 threads.
__global__ void prep_weights(const float* __restrict__ W1, const float* __restrict__ W2,
                             unsigned short* __restrict__ W1T, unsigned short* __restrict__ W2T) {
    __shared__ float tl[32][33];
    int s = blockIdx.y;
    int bt = blockIdx.x;
    const float* in; unsigned short* out; int K, N, perm, tk, tn;
    if (bt < 64) { in = W1; out = W1T; K = KDIM; N = HDIM; perm = 1; tk = bt >> 2; tn = bt & 3; }
    else         { bt -= 64; in = W2; out = W2T; K = HDIM; N = HDIM; perm = 0; tk = bt >> 2; tn = bt & 3; }
    const float* ins = in + (size_t)s * K * N;
    unsigned short* outs = out + (size_t)s * N * K;
    int t = threadIdx.x, r4 = t >> 5, c = t & 31;
    #pragma unroll
    for (int i = 0; i < 4; ++i) {
        int r = i * 8 + r4;
        tl[r][c] = ins[(tk * 32 + r) * N + tn * 32 + c];
    }
    __syncthreads();
    #pragma unroll
    for (int i = 0; i < 4; ++i) {
        int r = i * 8 + r4;
        int k = tk * 32 + c;
        int kp = perm ? ((k & 127) * 4 + (k >> 7)) : k;
        outs[(size_t)(tn * 32 + r) * K + kp] = f2bf(tl[c][r]);
    }
}

__global__ void build_lists(const float* __restrict__ x,
                            const float* __restrict__ mids,
                            const float* __restrict__ widths,
                            int* __restrict__ g_count,
                            unsigned short* __restrict__ lists) {
    __shared__ int cnt[NSLAB];
    __shared__ int base[NSLAB];
    int tid = threadIdx.x;
    if (tid < NSLAB) cnt[tid] = 0;
    __syncthreads();
    int n = blockIdx.x * 256 + tid;
    float xc = x[n * 6];
    int ofs[NSLAB];
    unsigned int amask = 0;
    #pragma unroll
    for (int s = 0; s < NSLAB; ++s) {
        float xmin = mids[s] - 0.5f * widths[s];
        float xmax = mids[s] + 0.5f * widths[s];
        if (xc >= xmin && xc <= xmax) {
            ofs[s] = atomicAdd(&cnt[s], 1);
            amask |= (1u << s);
        }
    }
    __syncthreads();
    if (tid < NSLAB) base[tid] = atomicAdd(&g_count[tid], cnt[tid]);
    __syncthreads();
    #pragma unroll
    for (int s = 0; s < NSLAB; ++s)
        if (amask & (1u << s))
            lists[s * NPTS + base[s] + ofs[s]] = (unsigned short)n;
}

// Dense work table: one wave. table[0] = total; table[1+i] = (s<<16) | blk.
__global__ void build_table(const int* __restrict__ g_count, int* __restrict__ table) {
    int l = threadIdx.x;                 // 64 threads
    int cnt = (l < NSLAB) ? g_count[l] : 0;
    int nb = (cnt + PTS_PER_BLK - 1) >> 6;
    int inc = nb;                        // inclusive prefix over lanes
    #pragma unroll
    for (int d = 1; d < 16; d <<= 1) {
        int v = __shfl_up(inc, d, 64);
        if (l >= d) inc += v;
    }
    int total = __shfl(inc, 15, 64);
    if (l == 0) table[0] = total;
    #pragma unroll
    for (int s = 0; s < NSLAB; ++s) {
        int nbs  = __shfl(nb, s, 64);
        int offs = __shfl(inc, s, 64) - nbs;   // exclusive prefix
        for (int b = l; b < nbs; b += 64)
            table[1 + offs + b] = (s << 16) | b;
    }
}

// Block: 512 thr = 8 waves; 64 points x 1 slab (from work table).
// Wave w owns output cols [16w, 16w+16).
// Layer-1 K-loop in PAIRS of 64-k' chunks: dbuf 2x16KB, 5 barriers total.
// MFMA 16x16x32 bf16. A-frag (feat, LDS): lane holds A[l&15][(l>>4)*8+j].
// B-frag (weights): row-major W1T[n][k'] loads, 1-pair-deep register prefetch.
__global__ __launch_bounds__(512, 4) void mlp_eval(
        const float* __restrict__ x,  const float* __restrict__ B,
        const unsigned short* __restrict__ W1T, const float* __restrict__ b1,
        const unsigned short* __restrict__ W2T, const float* __restrict__ b2,
        const float* __restrict__ W3, const float* __restrict__ b3,
        const float* __restrict__ mids, const float* __restrict__ widths,
        const int* __restrict__ g_count,
        const int* __restrict__ table,
        const unsigned short* __restrict__ lists,
        float* __restrict__ tau_all) {
    if ((int)blockIdx.x >= table[0]) return;
    int ent = table[1 + blockIdx.x];
    int s = ent >> 16;
    int pbase = (ent & 0xFFFF) * PTS_PER_BLK;
    int count = g_count[s];

    __shared__ short smem[16384];             // 32KB: feat dbuf (2x16KB); later hbuf (16KB)
    __shared__ float lds_B4[NF * 4];          // 2KB
    __shared__ float xp[PTS_PER_BLK][6];      // 1.5KB
    __shared__ int   ns[PTS_PER_BLK];         // 256B
    __shared__ float lds_r[8][PTS_PER_BLK];   // 2KB

    int t = threadIdx.x;
    int w = t >> 6;          // wave id: cols [16w,16w+16)
    int l = t & 63;
    int lrow = l & 15;
    int khi = l >> 4;

    float mid = mids[s], wd = widths[s];
    if (t < PTS_PER_BLK) {
        int idx = pbase + t;
        int ii = idx < count ? idx : count - 1;
        int n = lists[s * NPTS + ii];
        ns[t] = n;
        const float* xr = x + n * 6;
        #pragma unroll
        for (int d = 0; d < 6; ++d) xp[t][d] = (xr[d] - mid) / wd;
    }
    if (t < NF) {
        const float* br = B + s * (NF * 3) + t * 3;
        ((f32x4*)lds_B4)[t] = (f32x4){br[0], br[1], br[2], 0.0f};
    }
    __syncthreads();

    const unsigned short* W1Ts = W1T + (size_t)s * HDIM * KDIM;
    const unsigned short* W2Ts = W2T + (size_t)s * HDIM * HDIM;
    const float* b1s = b1 + s * HDIM;
    const float* b2s = b2 + s * HDIM;
    const float* W3s = W3 + s * HDIM;

    int p_ = t >> 3;         // point this thread fills (0..63)
    int fs = t & 7;          // freq-pair slot within chunk (0..7)
    float xv0 = xp[p_][0], xv1 = xp[p_][1], xv2 = xp[p_][2];
    float xv3 = xp[p_][3], xv4 = xp[p_][4], xv5 = xp[p_][5];
    unsigned swzp = ((unsigned)(p_ & 7)) << 4;

    // ---- layer 1: feat[64x512] * W1[512x128], K' interleaved (k' = f*4+type) ----
    f32x4 acc1[4];
    #pragma unroll
    for (int mt = 0; mt < 4; ++mt) {
        float bv = b1s[w * 16 + lrow];
        acc1[mt] = (f32x4){bv, bv, bv, bv};
    }

    // fill chunk-PAIR cp (k' cols [cp*128, cp*128+128)) into buffer (cp&1)
    #define FILL_PAIR(cp)                                                          \
    do {                                                                           \
        short* fb = smem + ((cp) & 1) * 8192;                                      \
        _Pragma("unroll")                                                          \
        for (int c2 = 0; c2 < 2; ++c2) {                                           \
            int cfull = 2 * (cp) + c2;                                             \
            f32x4 Ba = ((const f32x4*)lds_B4)[16 * cfull + fs * 2];                \
            f32x4 Bb = ((const f32x4*)lds_B4)[16 * cfull + fs * 2 + 1];            \
            float Fa0 = xv0 * Ba.x + xv1 * Ba.y + xv2 * Ba.z;                      \
            float Fa1 = xv3 * Ba.x + xv4 * Ba.y + xv5 * Ba.z;                      \
            float Fb0 = xv0 * Bb.x + xv1 * Bb.y + xv2 * Bb.z;                      \
            float Fb1 = xv3 * Bb.x + xv4 * Bb.y + xv5 * Bb.z;                      \
            float pa0 = __builtin_amdgcn_fractf(Fa0);                              \
            float pa1 = __builtin_amdgcn_fractf(Fa1);                              \
            float pb0 = __builtin_amdgcn_fractf(Fb0);                              \
            float pb1 = __builtin_amdgcn_fractf(Fb1);                              \
            unsigned k0 = pk_bf16(__builtin_amdgcn_sinf(pa0), __builtin_amdgcn_cosf(pa0)); \
            unsigned k1 = pk_bf16(__builtin_amdgcn_sinf(pa1), __builtin_amdgcn_cosf(pa1)); \
            unsigned k2 = pk_bf16(__builtin_amdgcn_sinf(pb0), __builtin_amdgcn_cosf(pb0)); \
            unsigned k3 = pk_bf16(__builtin_amdgcn_sinf(pb1), __builtin_amdgcn_cosf(pb1)); \
            unsigned byte = ((unsigned)(p_ * 256 + c2 * 128 + fs * 16)) ^ swzp;    \
            *(u32x4*)((char*)fb + byte) = (u32x4){k0, k1, k2, k3};                 \
        }                                                                          \
    } while (0)

    #define LOADW1P(dst, cp)                                                       \
    do {                                                                           \
        _Pragma("unroll")                                                          \
        for (int c2 = 0; c2 < 2; ++c2)                                             \
            _Pragma("unroll")                                                      \
            for (int ks = 0; ks < 2; ++ks) {                                       \
                int n_ = w * 16 + lrow;                                            \
                int k_ = (2 * (cp) + c2) * 64 + ks * 32 + khi * 8;                 \
                dst[c2][ks] = *(const bf16x8*)(W1Ts + (size_t)n_ * KDIM + k_);     \
            }                                                                      \
    } while (0)

    #define DO_MFMA_PAIR(bfr, fb)                                                  \
    do {                                                                           \
        __builtin_amdgcn_s_setprio(1);                                             \
        _Pragma("unroll")                                                          \
        for (int c2 = 0; c2 < 2; ++c2)                                             \
            _Pragma("unroll")                                                      \
            for (int ks = 0; ks < 2; ++ks) {                                       \
                bf16x8 af[4];                                                      \
                _Pragma("unroll")                                                  \
                for (int mt = 0; mt < 4; ++mt) {                                   \
                    int row = mt * 16 + lrow;                                      \
                    unsigned byte = (unsigned)(row * 256 + c2 * 128 + ks * 64 + khi * 16) \
                                  ^ ((unsigned)(row & 7) << 4);                    \
                    af[mt] = *(const bf16x8*)((const char*)(fb) + byte);           \
                }                                                                  \
                _Pragma("unroll")                                                  \
                for (int mt = 0; mt < 4; ++mt)                                     \
                    acc1[mt] = __builtin_amdgcn_mfma_f32_16x16x32_bf16(            \
                        af[mt], bfr[c2][ks], acc1[mt], 0, 0, 0);                   \
            }                                                                      \
        __builtin_amdgcn_s_setprio(0);                                             \
    } while (0)

    bf16x8 fA[2][2], fB[2][2];
    LOADW1P(fA, 0);
    FILL_PAIR(0);
    __syncthreads();

    LOADW1P(fB, 1); FILL_PAIR(1);
    DO_MFMA_PAIR(fA, smem);
    __syncthreads();

    LOADW1P(fA, 2); FILL_PAIR(2);
    DO_MFMA_PAIR(fB, smem + 8192);
    __syncthreads();

    LOADW1P(fB, 3); FILL_PAIR(3);
    DO_MFMA_PAIR(fA, smem);
    __syncthreads();

    DO_MFMA_PAIR(fB, smem + 8192);
    __syncthreads();

    // prefetch W2 fragments to hide under tanh/transpose
    bf16x8 w2f[4];
    #pragma unroll
    for (int ks = 0; ks < 4; ++ks) {
        int n_ = w * 16 + lrow;
        w2f[ks] = *(const bf16x8*)(W2Ts + (size_t)n_ * HDIM + ks * 32 + khi * 8);
    }

    // tanh -> bf16 -> hbuf (overlays feat buf0; swizzled [point][col], row stride 256B)
    short* hbuf = smem;
    #pragma unroll
    for (int mt = 0; mt < 4; ++mt)
        #pragma unroll
        for (int r = 0; r < 4; ++r) {
            int row = mt * 16 + khi * 4 + r;
            int col = w * 16 + lrow;
            unsigned byte = (unsigned)(row * 256 + col * 2) ^ ((unsigned)(row & 7) << 4);
            *(short*)((char*)hbuf + byte) = (short)f2bf(fast_tanh(acc1[mt][r]));
        }
    __syncthreads();

    // ---- layer 2: h1[64x128] * W2[128x128] ----
    f32x4 acc2[4];
    #pragma unroll
    for (int mt = 0; mt < 4; ++mt) {
        float bv = b2s[w * 16 + lrow];
        acc2[mt] = (f32x4){bv, bv, bv, bv};
    }
    __builtin_amdgcn_s_setprio(1);
    #pragma unroll
    for (int ks = 0; ks < 4; ++ks) {
        bf16x8 af[4];
        #pragma unroll
        for (int mt = 0; mt < 4; ++mt) {
            int row = mt * 16 + lrow;
            unsigned byte = (unsigned)(row * 256 + ks * 64 + khi * 16) ^ ((unsigned)(row & 7) << 4);
            af[mt] = *(const bf16x8*)((const char*)hbuf + byte);
        }
        #pragma unroll
        for (int mt = 0; mt < 4; ++mt)
            acc2[mt] = __builtin_amdgcn_mfma_f32_16x16x32_bf16(
                af[mt], w2f[ks], acc2[mt], 0, 0, 0);
    }
    __builtin_amdgcn_s_setprio(0);
    __syncthreads();
    #pragma unroll
    for (int mt = 0; mt < 4; ++mt)
        #pragma unroll
        for (int r = 0; r < 4; ++r) {
            int row = mt * 16 + khi * 4 + r;
            int col = w * 16 + lrow;
            unsigned byte = (unsigned)(row * 256 + col * 2) ^ ((unsigned)(row & 7) << 4);
            *(short*)((char*)hbuf + byte) = (short)f2bf(fast_tanh(acc2[mt][r]));
        }
    __syncthreads();

    // ---- layer 3: h2[64x128] * W3[128]; wave w covers cols [16w,16w+16) ----
    float part = 0.0f;
    #pragma unroll
    for (int u = 0; u < 2; ++u) {
        int cb = w * 16 + u * 8;
        unsigned byte = (unsigned)(l * 256 + cb * 2) ^ ((unsigned)(l & 7) << 4);
        bf16x8 hv = *(const bf16x8*)((const char*)hbuf + byte);
        #pragma unroll
        for (int e = 0; e < 8; ++e)
            part += bf2f((unsigned short)hv[e]) * W3s[cb + e];
    }
    lds_r[w][l] = part;
    __syncthreads();
    if (t < PTS_PER_BLK) {
        float tau = b3[s];
        #pragma unroll
        for (int ww = 0; ww < 8; ++ww) tau += lds_r[ww][t];
        if (pbase + t < count) tau_all[s * NPTS + ns[t]] = tau;
    }
}

__global__ void finalize(const float* __restrict__ x,
                         const float* __restrict__ mids,
                         const float* __restrict__ widths,
                         const float* __restrict__ tau_all,
                         float* __restrict__ out) {
    int n = blockIdx.x * 256 + threadIdx.x;
    if (n >= NPTS) return;
    float xc = x[n * 6];
    float num = 0.0f, den = 0.0f;
    #pragma unroll
    for (int s = 0; s < NSLAB; ++s) {
        float xmin = mids[s] - 0.5f * widths[s];
        float xmax = mids[s] + 0.5f * widths[s];
        if (xc >= xmin && xc <= xmax) {
            float xs = 2.0f * (xc - xmin) / (xmax - xmin) - 1.0f;
            float w = 0.5f * (1.0f + __builtin_amdgcn_cosf(__builtin_amdgcn_fractf(0.5f * xs)));
            num += w * tau_all[s * NPTS + n];
            den += w;
        }
    }
    out[n] = num / den;
}

extern "C" void kernel_launch(void* const* d_in, const int* in_sizes, int n_in,
                              void* d_out, int out_size, void* d_ws, size_t ws_size,
                              hipStream_t stream) {
    const float* x      = (const float*)d_in[0];
    const float* B      = (const float*)d_in[1];
    const float* W1     = (const float*)d_in[2];
    const float* b1     = (const float*)d_in[3];
    const float* W2     = (const float*)d_in[4];
    const float* b2     = (const float*)d_in[5];
    const float* W3     = (const float*)d_in[6];
    const float* b3     = (const float*)d_in[7];
    const float* mids   = (const float*)d_in[8];
    const float* widths = (const float*)d_in[9];
    float* out = (float*)d_out;

    char* ws = (char*)d_ws;
    int*            g_count = (int*)(ws + WS_COUNT_OFF);
    unsigned short* lists   = (unsigned short*)(ws + WS_LIST_OFF);
    int*            table   = (int*)(ws + WS_TABLE_OFF);
    float*          tau_all = (float*)(ws + WS_TAU_OFF);
    unsigned short* W1T     = (unsigned short*)(ws + WS_W1T_OFF);
    unsigned short* W2T     = (unsigned short*)(ws + WS_W2T_OFF);

    (void)hipMemsetAsync(g_count, 0, NSLAB * sizeof(int), stream);

    prep_weights<<<dim3(80, NSLAB), 256, 0, stream>>>(W1, W2, W1T, W2T);
    build_lists<<<dim3(NPTS / 256), 256, 0, stream>>>(x, mids, widths, g_count, lists);
    build_table<<<1, 64, 0, stream>>>(g_count, table);
    mlp_eval<<<dim3(MAXBLK), 512, 0, stream>>>(
        x, B, W1T, b1, W2T, b2, W3, b3, mids, widths, g_count, table, lists, tau_all);
    finalize<<<dim3(NPTS / 256), 256, 0, stream>>>(x, mids, widths, tau_all, out);
}

// Round 15
// 67.523 us; speedup vs baseline: 1.0565x; 1.0565x over previous
//
#include <hip/hip_runtime.h>
#include <hip/hip_bf16.h>

#define NPTS 32768
#define NSLAB 16
#define NF 128
#define HDIM 128
#define KDIM 512          // 4*NF
#define PTS_PER_BLK 64
#define MAXBLK 2064       // sum ceil(count_s/64) <= 4*32768/64 + 16

// ---- workspace layout (bytes) ----
// [0, 64)        : g_count[16] (int)
// [1024, +1MB)   : lists, u16 [16][NPTS]
// [1.5MB, +8.3KB): work table: [0]=total, [1+i]=(s<<16)|blk
// [2MB, 4MB)     : tau_all, f32 [16][NPTS]
// [4MB, 6MB)     : W1T bf16 [16][128][512]  (K-permuted: k' = f*4+type)
// [6MB, 6.5MB)   : W2T bf16 [16][128][128]
#define WS_COUNT_OFF   0
#define WS_LIST_OFF    1024
#define WS_TABLE_OFF   0x180000
#define WS_TAU_OFF     (2u << 20)
#define WS_W1T_OFF     (4u << 20)
#define WS_W2T_OFF     (6u << 20)

typedef __attribute__((ext_vector_type(8))) short bf16x8;
typedef __attribute__((ext_vector_type(4))) float f32x4;
typedef __attribute__((ext_vector_type(4))) unsigned int u32x4;

__device__ __forceinline__ unsigned short f2bf(float f) {
    union { float f; unsigned u; } v; v.f = f;
    unsigned u = v.u;
    return (unsigned short)((u + 0x7FFFu + ((u >> 16) & 1u)) >> 16);
}
__device__ __forceinline__ float bf2f(unsigned short h) {
    union { unsigned u; float f; } v; v.u = ((unsigned)h) << 16; return v.f;
}
__device__ __forceinline__ float fast_tanh(float v) {
    v = fminf(fmaxf(v, -15.0f), 15.0f);
    float t = __builtin_amdgcn_exp2f(v * 2.8853900817779268f); // e^{2v}
    return (t - 1.0f) * __builtin_amdgcn_rcpf(t + 1.0f);
}
// pack two f32 -> one u32 of two bf16 (lo = a, hi = b)
__device__ __forceinline__ unsigned pk_bf16(float a, float b) {
    unsigned r;
    asm("v_cvt_pk_bf16_f32 %0, %1, %2" : "=v"(r) : "v"(a), "v"(b));
    return r;
}

// Transpose + f32->bf16 for W1 (K-permuted) and W2 in one launch (r13-proven).
__global__ void prep_weights(const float* __restrict__ W1, const float* __restrict__ W2,
                             unsigned short* __restrict__ W1T, unsigned short* __restrict__ W2T) {
    __shared__ float tl[32][33];
    int s = blockIdx.y;
    int bt = blockIdx.x;
    const float* in; unsigned short* out; int K, N, perm, tk, tn;
    if (bt < 64) { in = W1; out = W1T; K = KDIM; N = HDIM; perm = 1; tk = bt >> 2; tn = bt & 3; }
    else         { bt -= 64; in = W2; out = W2T; K = HDIM; N = HDIM; perm = 0; tk = bt >> 2; tn = bt & 3; }
    const float* ins = in + (size_t)s * K * N;
    unsigned short* outs = out + (size_t)s * N * K;
    int t = threadIdx.x, r4 = t >> 5, c = t & 31;
    #pragma unroll
    for (int i = 0; i < 4; ++i) {
        int r = i * 8 + r4;
        tl[r][c] = ins[(tk * 32 + r) * N + tn * 32 + c];
    }
    __syncthreads();
    #pragma unroll
    for (int i = 0; i < 4; ++i) {
        int r = i * 8 + r4;
        int k = tk * 32 + c;
        int kp = perm ? ((k & 127) * 4 + (k >> 7)) : k;
        outs[(size_t)(tn * 32 + r) * K + kp] = f2bf(tl[c][r]);
    }
}

__global__ void build_lists(const float* __restrict__ x,
                            const float* __restrict__ mids,
                            const float* __restrict__ widths,
                            int* __restrict__ g_count,
                            unsigned short* __restrict__ lists) {
    __shared__ int cnt[NSLAB];
    __shared__ int base[NSLAB];
    int tid = threadIdx.x;
    if (tid < NSLAB) cnt[tid] = 0;
    __syncthreads();
    int n = blockIdx.x * 256 + tid;
    float xc = x[n * 6];
    int ofs[NSLAB];
    unsigned int amask = 0;
    #pragma unroll
    for (int s = 0; s < NSLAB; ++s) {
        float xmin = mids[s] - 0.5f * widths[s];
        float xmax = mids[s] + 0.5f * widths[s];
        if (xc >= xmin && xc <= xmax) {
            ofs[s] = atomicAdd(&cnt[s], 1);
            amask |= (1u << s);
        }
    }
    __syncthreads();
    if (tid < NSLAB) base[tid] = atomicAdd(&g_count[tid], cnt[tid]);
    __syncthreads();
    #pragma unroll
    for (int s = 0; s < NSLAB; ++s)
        if (amask & (1u << s))
            lists[s * NPTS + base[s] + ofs[s]] = (unsigned short)n;
}

// Dense work table: one wave. table[0] = total; table[1+i] = (s<<16) | blk.
__global__ void build_table(const int* __restrict__ g_count, int* __restrict__ table) {
    int l = threadIdx.x;                 // 64 threads
    int cnt = (l < NSLAB) ? g_count[l] : 0;
    int nb = (cnt + PTS_PER_BLK - 1) >> 6;
    int inc = nb;                        // inclusive prefix over lanes
    #pragma unroll
    for (int d = 1; d < 16; d <<= 1) {
        int v = __shfl_up(inc, d, 64);
        if (l >= d) inc += v;
    }
    int total = __shfl(inc, 15, 64);
    if (l == 0) table[0] = total;
    #pragma unroll
    for (int s = 0; s < NSLAB; ++s) {
        int nbs  = __shfl(nb, s, 64);
        int offs = __shfl(inc, s, 64) - nbs;   // exclusive prefix
        for (int b = l; b < nbs; b += 64)
            table[1 + offs + b] = (s << 16) | b;
    }
}

// Block: 256 thr = 4 waves; 64 points x 1 slab (from work table).
// Wave w owns output cols [32w, 32w+32).  (r10-proven body.)
// MFMA 16x16x32 bf16. A-frag (feat, LDS): lane holds A[l&15][(l>>4)*8+j].
// B-frag (weights): row-major W1T[n][k'] loads, 1-chunk-deep register prefetch.
__global__ __launch_bounds__(256, 3) void mlp_eval(
        const float* __restrict__ x,  const float* __restrict__ B,
        const unsigned short* __restrict__ W1T, const float* __restrict__ b1,
        const unsigned short* __restrict__ W2T, const float* __restrict__ b2,
        const float* __restrict__ W3, const float* __restrict__ b3,
        const float* __restrict__ mids, const float* __restrict__ widths,
        const int* __restrict__ g_count,
        const int* __restrict__ table,
        const unsigned short* __restrict__ lists,
        float* __restrict__ tau_all) {
    if ((int)blockIdx.x >= table[0]) return;
    int ent = table[1 + blockIdx.x];
    int s = ent >> 16;
    int pbase = (ent & 0xFFFF) * PTS_PER_BLK;
    int count = g_count[s];

    // smem: double-buffered feat (2 x 64x64 bf16 = 16KB), later overlaid by hbuf (16KB)
    __shared__ short smem[8192];
    __shared__ float lds_B[NF * 3];           // 1.5KB  B rows [f][3]
    __shared__ float xp[PTS_PER_BLK][6];
    __shared__ int   ns[PTS_PER_BLK];
    __shared__ float lds_r[4][PTS_PER_BLK];

    int t = threadIdx.x;
    int w = t >> 6;          // wave id = output col block
    int l = t & 63;          // lane
    int lrow = l & 15;
    int khi = l >> 4;        // 0..3

    float mid = mids[s], wd = widths[s];
    if (t < PTS_PER_BLK) {
        int idx = pbase + t;
        int ii = idx < count ? idx : count - 1;
        int n = lists[s * NPTS + ii];
        ns[t] = n;
        const float* xr = x + n * 6;
        #pragma unroll
        for (int d = 0; d < 6; ++d) xp[t][d] = (xr[d] - mid) / wd;
    }
    // stage B slab into LDS (128*3 floats = 96 float4)
    if (t < 96) ((f32x4*)lds_B)[t] = ((const f32x4*)(B + s * (NF * 3)))[t];
    __syncthreads();

    const unsigned short* W1Ts = W1T + (size_t)s * HDIM * KDIM;
    const unsigned short* W2Ts = W2T + (size_t)s * HDIM * HDIM;
    const float* b1s = b1 + s * HDIM;
    const float* b2s = b2 + s * HDIM;
    const float* W3s = W3 + s * HDIM;

    int p = t >> 2;          // point this thread fills feat for
    int g = t & 3;           // freq subgroup (4 freqs per thread per chunk)
    float xv0 = xp[p][0], xv1 = xp[p][1], xv2 = xp[p][2];
    float xv3 = xp[p][3], xv4 = xp[p][4], xv5 = xp[p][5];
    unsigned wbyte0 = ((unsigned)(p * 128 + g * 32)) ^ ((unsigned)(p & 7) << 4);
    unsigned wbyte1 = ((unsigned)(p * 128 + g * 32 + 16)) ^ ((unsigned)(p & 7) << 4);

    // ---- layer 1: feat[64x512] * W1[512x128], K interleaved (k' = f*4+type) ----
    f32x4 acc1[4][2];
    #pragma unroll
    for (int mt = 0; mt < 4; ++mt)
        #pragma unroll
        for (int nt = 0; nt < 2; ++nt) {
            float bv = b1s[w * 32 + nt * 16 + lrow];
            acc1[mt][nt] = (f32x4){bv, bv, bv, bv};
        }

    // feat fill for chunk c into buffer (c&1): freqs [16c, 16c+16), this thread does 4
    #define FILL_CHUNK(c)                                                          \
    do {                                                                           \
        short* fb = smem + ((c) & 1) * 4096;                                       \
        const f32x4* bq = (const f32x4*)lds_B + (12 * (c) + 3 * g);                \
        f32x4 q0 = bq[0], q1 = bq[1], q2 = bq[2];                                  \
        float bf_[12] = {q0.x, q0.y, q0.z, q0.w, q1.x, q1.y, q1.z, q1.w,           \
                         q2.x, q2.y, q2.z, q2.w};                                  \
        unsigned pk[8];                                                            \
        _Pragma("unroll")                                                          \
        for (int jf = 0; jf < 4; ++jf) {                                           \
            float b0 = bf_[jf * 3], b1v = bf_[jf * 3 + 1], b2v = bf_[jf * 3 + 2];  \
            float F0 = xv0 * b0 + xv1 * b1v + xv2 * b2v;                           \
            float F1 = xv3 * b0 + xv4 * b1v + xv5 * b2v;                           \
            float p0 = __builtin_amdgcn_fractf(F0);                                \
            float p1 = __builtin_amdgcn_fractf(F1);                                \
            float s0 = __builtin_amdgcn_sinf(p0), c0 = __builtin_amdgcn_cosf(p0);  \
            float s1 = __builtin_amdgcn_sinf(p1), c1 = __builtin_amdgcn_cosf(p1);  \
            pk[jf * 2]     = pk_bf16(s0, c0);                                      \
            pk[jf * 2 + 1] = pk_bf16(s1, c1);                                      \
        }                                                                          \
        *(u32x4*)((char*)fb + wbyte0) = (u32x4){pk[0], pk[1], pk[2], pk[3]};       \
        *(u32x4*)((char*)fb + wbyte1) = (u32x4){pk[4], pk[5], pk[6], pk[7]};       \
    } while (0)

    // r10-exact W1 B-frag load (row-major W1T[n][k'])
    #define LOADW1(dst, c)                                                         \
    do {                                                                           \
        _Pragma("unroll")                                                          \
        for (int ks = 0; ks < 2; ++ks)                                             \
            _Pragma("unroll")                                                      \
            for (int nt = 0; nt < 2; ++nt) {                                       \
                int n_ = w * 32 + nt * 16 + lrow;                                  \
                int k_ = (c) * 64 + ks * 32 + khi * 8;                             \
                dst[ks][nt] = *(const bf16x8*)(W1Ts + (size_t)n_ * KDIM + k_);     \
            }                                                                      \
    } while (0)

    #define DO_MFMA(bfr, fb)                                                       \
    do {                                                                           \
        __builtin_amdgcn_s_setprio(1);                                             \
        _Pragma("unroll")                                                          \
        for (int ks = 0; ks < 2; ++ks) {                                           \
            bf16x8 af[4];                                                          \
            _Pragma("unroll")                                                      \
            for (int mt = 0; mt < 4; ++mt) {                                       \
                int row = mt * 16 + lrow;                                          \
                unsigned byte = (unsigned)(row * 128 + ks * 64 + khi * 16)         \
                              ^ ((unsigned)(row & 7) << 4);                        \
                af[mt] = *(const bf16x8*)((const char*)(fb) + byte);               \
            }                                                                      \
            _Pragma("unroll")                                                      \
            for (int mt = 0; mt < 4; ++mt)                                         \
                _Pragma("unroll")                                                  \
                for (int nt = 0; nt < 2; ++nt)                                     \
                    acc1[mt][nt] = __builtin_amdgcn_mfma_f32_16x16x32_bf16(        \
                        af[mt], bfr[ks][nt], acc1[mt][nt], 0, 0, 0);               \
        }                                                                          \
        __builtin_amdgcn_s_setprio(0);                                             \
    } while (0)

    bf16x8 bfrA[2][2], bfrB[2][2];
    LOADW1(bfrA, 0);
    FILL_CHUNK(0);
    __syncthreads();
    #pragma unroll
    for (int cc = 0; cc < 4; ++cc) {
        const int c0 = 2 * cc;
        LOADW1(bfrB, c0 + 1);              // prefetch next chunk's weights
        FILL_CHUNK(c0 + 1);                // fill buf1 while loads fly
        DO_MFMA(bfrA, smem);               // chunk c0 from buf0
        __syncthreads();
        if (cc < 3) {
            LOADW1(bfrA, c0 + 2);
            FILL_CHUNK(c0 + 2);            // buf0 (safe: all reads drained above)
        }
        DO_MFMA(bfrB, smem + 4096);        // chunk c0+1 from buf1
        __syncthreads();
    }

    // prefetch all W2 fragments to hide under tanh/transpose
    bf16x8 w2f[4][2];
    #pragma unroll
    for (int ks = 0; ks < 4; ++ks)
        #pragma unroll
        for (int nt = 0; nt < 2; ++nt) {
            int n_ = w * 32 + nt * 16 + lrow;
            w2f[ks][nt] = *(const bf16x8*)(W2Ts + (size_t)n_ * HDIM + ks * 32 + khi * 8);
        }

    // tanh -> bf16 -> hbuf (overlays feat; swizzled [point][col], row stride 256B)
    short* hbuf = smem;
    #pragma unroll
    for (int mt = 0; mt < 4; ++mt)
        #pragma unroll
        for (int nt = 0; nt < 2; ++nt)
            #pragma unroll
            for (int r = 0; r < 4; ++r) {
                int row = mt * 16 + khi * 4 + r;
                int col = w * 32 + nt * 16 + lrow;
                unsigned byte = (unsigned)(row * 256 + col * 2) ^ ((unsigned)(row & 7) << 4);
                *(short*)((char*)hbuf + byte) = (short)f2bf(fast_tanh(acc1[mt][nt][r]));
            }
    __syncthreads();

    // ---- layer 2: h1[64x128] * W2[128x128] ----
    f32x4 acc2[4][2];
    #pragma unroll
    for (int mt = 0; mt < 4; ++mt)
        #pragma unroll
        for (int nt = 0; nt < 2; ++nt) {
            float bv = b2s[w * 32 + nt * 16 + lrow];
            acc2[mt][nt] = (f32x4){bv, bv, bv, bv};
        }
    __builtin_amdgcn_s_setprio(1);
    #pragma unroll
    for (int ks = 0; ks < 4; ++ks) {
        bf16x8 af[4];
        #pragma unroll
        for (int mt = 0; mt < 4; ++mt) {
            int row = mt * 16 + lrow;
            unsigned byte = (unsigned)(row * 256 + ks * 64 + khi * 16) ^ ((unsigned)(row & 7) << 4);
            af[mt] = *(const bf16x8*)((const char*)hbuf + byte);
        }
        #pragma unroll
        for (int mt = 0; mt < 4; ++mt)
            #pragma unroll
            for (int nt = 0; nt < 2; ++nt)
                acc2[mt][nt] = __builtin_amdgcn_mfma_f32_16x16x32_bf16(
                    af[mt], w2f[ks][nt], acc2[mt][nt], 0, 0, 0);
    }
    __builtin_amdgcn_s_setprio(0);
    __syncthreads();   // all hbuf(h1) reads done
    #pragma unroll
    for (int mt = 0; mt < 4; ++mt)
        #pragma unroll
        for (int nt = 0; nt < 2; ++nt)
            #pragma unroll
            for (int r = 0; r < 4; ++r) {
                int row = mt * 16 + khi * 4 + r;
                int col = w * 32 + nt * 16 + lrow;
                unsigned byte = (unsigned)(row * 256 + col * 2) ^ ((unsigned)(row & 7) << 4);
                *(short*)((char*)hbuf + byte) = (short)f2bf(fast_tanh(acc2[mt][nt][r]));
            }
    __syncthreads();

    // ---- layer 3: h2[64x128] * W3[128] ----
    float part = 0.0f;
    #pragma unroll
    for (int u = 0; u < 4; ++u) {
        int cb = w * 32 + u * 8;
        unsigned byte = (unsigned)(l * 256 + cb * 2) ^ ((unsigned)(l & 7) << 4);
        bf16x8 hv = *(const bf16x8*)((const char*)hbuf + byte);
        #pragma unroll
        for (int e = 0; e < 8; ++e)
            part += bf2f((unsigned short)hv[e]) * W3s[cb + e];
    }
    lds_r[w][l] = part;
    __syncthreads();
    if (t < PTS_PER_BLK) {
        float tau = b3[s] + lds_r[0][t] + lds_r[1][t] + lds_r[2][t] + lds_r[3][t];
        if (pbase + t < count) tau_all[s * NPTS + ns[t]] = tau;
    }
}

__global__ void finalize(const float* __restrict__ x,
                         const float* __restrict__ mids,
                         const float* __restrict__ widths,
                         const float* __restrict__ tau_all,
                         float* __restrict__ out) {
    int n = blockIdx.x * 256 + threadIdx.x;
    if (n >= NPTS) return;
    float xc = x[n * 6];
    float num = 0.0f, den = 0.0f;
    #pragma unroll
    for (int s = 0; s < NSLAB; ++s) {
        float xmin = mids[s] - 0.5f * widths[s];
        float xmax = mids[s] + 0.5f * widths[s];
        if (xc >= xmin && xc <= xmax) {
            float xs = 2.0f * (xc - xmin) / (xmax - xmin) - 1.0f;
            float w = 0.5f * (1.0f + __builtin_amdgcn_cosf(__builtin_amdgcn_fractf(0.5f * xs)));
            num += w * tau_all[s * NPTS + n];
            den += w;
        }
    }
    out[n] = num / den;
}

extern "C" void kernel_launch(void* const* d_in, const int* in_sizes, int n_in,
                              void* d_out, int out_size, void* d_ws, size_t ws_size,
                              hipStream_t stream) {
    const float* x      = (const float*)d_in[0];
    const float* B      = (const float*)d_in[1];
    const float* W1     = (const float*)d_in[2];
    const float* b1     = (const float*)d_in[3];
    const float* W2     = (const float*)d_in[4];
    const float* b2     = (const float*)d_in[5];
    const float* W3     = (const float*)d_in[6];
    const float* b3     = (const float*)d_in[7];
    const float* mids   = (const float*)d_in[8];
    const float* widths = (const float*)d_in[9];
    float* out = (float*)d_out;

    char* ws = (char*)d_ws;
    int*            g_count = (int*)(ws + WS_COUNT_OFF);
    unsigned short* lists   = (unsigned short*)(ws + WS_LIST_OFF);
    int*            table   = (int*)(ws + WS_TABLE_OFF);
    float*          tau_all = (float*)(ws + WS_TAU_OFF);
    unsigned short* W1T     = (unsigned short*)(ws + WS_W1T_OFF);
    unsigned short* W2T     = (unsigned short*)(ws + WS_W2T_OFF);

    (void)hipMemsetAsync(g_count, 0, NSLAB * sizeof(int), stream);

    prep_weights<<<dim3(80, NSLAB), 256, 0, stream>>>(W1, W2, W1T, W2T);
    build_lists<<<dim3(NPTS / 256), 256, 0, stream>>>(x, mids, widths, g_count, lists);
    build_table<<<1, 64, 0, stream>>>(g_count, table);
    mlp_eval<<<dim3(MAXBLK), 256, 0, stream>>>(
        x, B, W1T, b1, W2T, b2, W3, b3, mids, widths, g_count, table, lists, tau_all);
    finalize<<<dim3(NPTS / 256), 256, 0, stream>>>(x, mids, widths, tau_all, out);
}